// Round 1
// baseline (1165.545 us; speedup 1.0000x reference)
//
#include <hip/hip_runtime.h>

typedef unsigned short u16;
typedef unsigned int u32;
typedef __bf16 bf16x8 __attribute__((ext_vector_type(8)));
typedef float f32x4 __attribute__((ext_vector_type(4)));

#define MFMA16(a,b,c) __builtin_amdgcn_mfma_f32_16x16x32_bf16((a),(b),(c),0,0,0)

__device__ __forceinline__ u16 f2bf(float x) {
  u32 u = __float_as_uint(x);
  u32 r = (u + 0x7fffu + ((u >> 16) & 1u)) >> 16;
  return (u16)r;
}

// ---------------- weight transpose + bf16 cast ----------------
__global__ __launch_bounds__(256) void prep_weights(
    const float* __restrict__ qkv_w, const float* __restrict__ proj_w,
    const float* __restrict__ fc1_w, const float* __restrict__ fc2_w,
    u16* __restrict__ qkv_wT, u16* __restrict__ proj_wT,
    u16* __restrict__ fc1_wT, u16* __restrict__ fc2_wT) {
  int t0 = blockIdx.x * 256 + threadIdx.x;
  int stride = gridDim.x * 256;
  for (int i = t0; i < 576 * 192; i += stride) {        // qkv_wT [576][192]
    int n = i / 192, k = i - n * 192;
    qkv_wT[i] = f2bf(qkv_w[k * 576 + n]);
  }
  for (int i = t0; i < 192 * 192; i += stride) {        // proj_wT [192][192]
    int n = i / 192, k = i - n * 192;
    proj_wT[i] = f2bf(proj_w[k * 192 + n]);
  }
  for (int i = t0; i < 768 * 192; i += stride) {        // fc1_wT [768][192]
    int n = i / 192, k = i - n * 192;
    fc1_wT[i] = f2bf(fc1_w[k * 768 + n]);
  }
  for (int i = t0; i < 192 * 768; i += stride) {        // fc2_wT [192][768]
    int n = i / 768, k = i - n * 768;
    fc2_wT[i] = f2bf(fc2_w[k * 192 + n]);
  }
}

// ---------------- LN1 + shift + window partition ----------------
// row = w*49+n  (w: window 0..2047, n: token 0..48) -> xn bf16 [row][192]
__global__ __launch_bounds__(192) void ln1_kernel(
    const float* __restrict__ x, const float* __restrict__ g,
    const float* __restrict__ bb, u16* __restrict__ xn) {
  int row = blockIdx.x;
  int w = row / 49, n = row - w * 49;
  int b = w >> 6, wi = w & 63;
  int hh = (wi >> 3) * 7 + n / 7 + 3; if (hh >= 56) hh -= 56;
  int ww = (wi & 7) * 7 + (n - (n / 7) * 7) + 3; if (ww >= 56) ww -= 56;
  const float* src = x + ((size_t)b * 3136 + hh * 56 + ww) * 192;
  int t = threadIdx.x;
  float v = src[t];
  float a1 = v, a2 = v * v;
  #pragma unroll
  for (int off = 32; off; off >>= 1) {
    a1 += __shfl_down(a1, off);
    a2 += __shfl_down(a2, off);
  }
  __shared__ float rA[3], rB[3];
  if ((t & 63) == 0) { rA[t >> 6] = a1; rB[t >> 6] = a2; }
  __syncthreads();
  float s1 = rA[0] + rA[1] + rA[2];
  float s2 = rB[0] + rB[1] + rB[2];
  float mu = s1 * (1.f / 192.f);
  float var = s2 * (1.f / 192.f) - mu * mu;
  float rs = rsqrtf(var + 1e-5f);
  xn[(size_t)row * 192 + t] = f2bf((v - mu) * rs * g[t] + bb[t]);
}

// ---------------- LN2 (plain rows) ----------------
__global__ __launch_bounds__(192) void ln2_kernel(
    const float* __restrict__ xr, const float* __restrict__ g,
    const float* __restrict__ bb, u16* __restrict__ h) {
  int row = blockIdx.x;
  int t = threadIdx.x;
  float v = xr[(size_t)row * 192 + t];
  float a1 = v, a2 = v * v;
  #pragma unroll
  for (int off = 32; off; off >>= 1) {
    a1 += __shfl_down(a1, off);
    a2 += __shfl_down(a2, off);
  }
  __shared__ float rA[3], rB[3];
  if ((t & 63) == 0) { rA[t >> 6] = a1; rB[t >> 6] = a2; }
  __syncthreads();
  float s1 = rA[0] + rA[1] + rA[2];
  float s2 = rB[0] + rB[1] + rB[2];
  float mu = s1 * (1.f / 192.f);
  float var = s2 * (1.f / 192.f) - mu * mu;
  float rs = rsqrtf(var + 1e-5f);
  h[(size_t)row * 192 + t] = f2bf((v - mu) * rs * g[t] + bb[t]);
}

// ---------------- fused qkv + window attention ----------------
// one block per (window, head). 256 threads = 4 waves.
__global__ __launch_bounds__(256) void attn_kernel(
    const u16* __restrict__ xn, const u16* __restrict__ qkv_wT,
    const float* __restrict__ qkv_b, const float* __restrict__ amask,
    u16* __restrict__ attnout) {
  __shared__ __align__(16) char lds[64000];
  u16* sXN = (u16*)lds;                  // [64][200] bf16 (phase A)
  u16* sW  = (u16*)(lds + 25600);        // [96][200] bf16 (phase A)
  u16* sQK = (u16*)lds;                  // [2][64][40] bf16 (phase B+)
  u16* sVT = (u16*)(lds + 10240);        // [32][72] bf16 V^T
  float* sS = (float*)(lds + 15360);     // [64][65] f32
  u16* sP  = (u16*)(lds + 32000);        // [64][72] bf16

  const int tid = threadIdx.x;
  const int blk = blockIdx.x;
  const int w = blk / 6;
  const int hd = blk - w * 6;
  const int wv = tid >> 6;
  const int ln = tid & 63;
  const int lrow = ln & 15;
  const int quad = ln >> 4;

  // stage xn tile (rows>=49 zeroed) and per-head W^T slice
  {
    const u32* xng = (const u32*)(xn + (size_t)w * (49 * 192));
    u32* d = (u32*)sXN;
    for (int i = tid; i < 64 * 96; i += 256) {
      int r = i / 96, c = i - r * 96;
      d[r * 100 + c] = (r < 49) ? xng[r * 96 + c] : 0u;
    }
    const u32* wg = (const u32*)qkv_wT;
    u32* dw = (u32*)sW;
    for (int i = tid; i < 96 * 96; i += 256) {
      int r = i / 96, c = i - r * 96;
      int sr = (r >> 5) * 192 + hd * 32 + (r & 31);
      dw[r * 100 + c] = wg[sr * 96 + c];
    }
  }
  __syncthreads();

  // QKV gemm: 64x96, K=192. wave wv owns rows 16*wv..16*wv+15.
  f32x4 accQ[6];
  #pragma unroll
  for (int t = 0; t < 6; t++) accQ[t] = (f32x4){0.f, 0.f, 0.f, 0.f};
  #pragma unroll
  for (int kc = 0; kc < 6; kc++) {
    bf16x8 af = *(const bf16x8*)(sXN + (16 * wv + lrow) * 200 + kc * 32 + quad * 8);
    #pragma unroll
    for (int t = 0; t < 6; t++) {
      bf16x8 bf_ = *(const bf16x8*)(sW + (t * 16 + lrow) * 200 + kc * 32 + quad * 8);
      accQ[t] = MFMA16(af, bf_, accQ[t]);
    }
  }
  __syncthreads();

  // write Q,K row-major [64][40]; V transposed [32][72]
  #pragma unroll
  for (int t = 0; t < 6; t++) {
    int cc = t * 16 + lrow;
    int sec = cc >> 5;
    int d = cc & 31;
    float bias = qkv_b[sec * 192 + hd * 32 + d];
    #pragma unroll
    for (int r = 0; r < 4; r++) {
      int row = 16 * wv + quad * 4 + r;
      u16 v = f2bf(accQ[t][r] + bias);
      if (sec == 2) sVT[d * 72 + row] = v;
      else sQK[(sec * 64 + row) * 40 + d] = v;
    }
  }
  __syncthreads();

  // S = Q K^T  (64x64, K=32)
  f32x4 accS[4];
  #pragma unroll
  for (int t = 0; t < 4; t++) accS[t] = (f32x4){0.f, 0.f, 0.f, 0.f};
  {
    bf16x8 af = *(const bf16x8*)(sQK + (16 * wv + lrow) * 40 + quad * 8);
    #pragma unroll
    for (int mt = 0; mt < 4; mt++) {
      bf16x8 bf_ = *(const bf16x8*)(sQK + (64 + mt * 16 + lrow) * 40 + quad * 8);
      accS[mt] = MFMA16(af, bf_, accS[mt]);
    }
  }
  #pragma unroll
  for (int mt = 0; mt < 4; mt++) {
    #pragma unroll
    for (int r = 0; r < 4; r++)
      sS[(16 * wv + quad * 4 + r) * 65 + mt * 16 + lrow] = accS[mt][r];
  }
  __syncthreads();

  // softmax rows (scale + mask), write P bf16 with zero padding
  if (tid < 64) {
    int n = tid;
    u16* prow = sP + n * 72;
    if (n < 49) {
      const float* mrow = amask + ((size_t)(w & 63) * 49 + n) * 49;
      float* srow = sS + n * 65;
      const float scale = 0.17677669529663687f;
      float mx = -1e30f;
      for (int m = 0; m < 49; m++) {
        float sv = srow[m] * scale + mrow[m];
        srow[m] = sv;
        mx = fmaxf(mx, sv);
      }
      float sum = 0.f;
      for (int m = 0; m < 49; m++) {
        float e = __expf(srow[m] - mx);
        srow[m] = e;
        sum += e;
      }
      float inv = 1.f / sum;
      for (int m = 0; m < 49; m++) prow[m] = f2bf(srow[m] * inv);
      for (int m = 49; m < 64; m++) prow[m] = 0;
    } else {
      for (int m = 0; m < 64; m++) prow[m] = 0;
    }
  }
  __syncthreads();

  // O = P V  (64x32, K=64)
  f32x4 accO[2];
  accO[0] = (f32x4){0.f, 0.f, 0.f, 0.f};
  accO[1] = (f32x4){0.f, 0.f, 0.f, 0.f};
  #pragma unroll
  for (int kc = 0; kc < 2; kc++) {
    bf16x8 af = *(const bf16x8*)(sP + (16 * wv + lrow) * 72 + kc * 32 + quad * 8);
    #pragma unroll
    for (int ct = 0; ct < 2; ct++) {
      bf16x8 bf_ = *(const bf16x8*)(sVT + (ct * 16 + lrow) * 72 + kc * 32 + quad * 8);
      accO[ct] = MFMA16(af, bf_, accO[ct]);
    }
  }
  #pragma unroll
  for (int ct = 0; ct < 2; ct++) {
    #pragma unroll
    for (int r = 0; r < 4; r++) {
      int row = 16 * wv + quad * 4 + r;
      if (row < 49)
        attnout[((size_t)w * 49 + row) * 192 + hd * 32 + ct * 16 + lrow] =
            f2bf(accO[ct][r]);
    }
  }
}

// ---------------- proj gemm + reverse partition/roll scatter ----------------
__global__ __launch_bounds__(256) void proj_kernel(
    const u16* __restrict__ attnout, const u16* __restrict__ proj_wT,
    const float* __restrict__ proj_b, float* __restrict__ out) {
  __shared__ __align__(16) u16 sA[64 * 200];
  const int tid = threadIdx.x;
  const int r0 = blockIdx.x * 64;
  {
    const u32* ag = (const u32*)(attnout + (size_t)r0 * 192);
    u32* d = (u32*)sA;
    for (int i = tid; i < 64 * 96; i += 256) {
      int r = i / 96, c = i - r * 96;
      d[r * 100 + c] = ag[i];
    }
  }
  __syncthreads();
  const int wv = tid >> 6, ln = tid & 63, lrow = ln & 15, quad = ln >> 4;
  f32x4 acc[12];
  #pragma unroll
  for (int t = 0; t < 12; t++) acc[t] = (f32x4){0.f, 0.f, 0.f, 0.f};
  for (int kc = 0; kc < 6; kc++) {
    bf16x8 af = *(const bf16x8*)(sA + (16 * wv + lrow) * 200 + kc * 32 + quad * 8);
    #pragma unroll
    for (int ct = 0; ct < 12; ct++) {
      bf16x8 bf_ = *(const bf16x8*)(proj_wT + (size_t)(ct * 16 + lrow) * 192 + kc * 32 + quad * 8);
      acc[ct] = MFMA16(af, bf_, acc[ct]);
    }
  }
  #pragma unroll
  for (int r = 0; r < 4; r++) {
    int gr = r0 + 16 * wv + quad * 4 + r;
    int w = gr / 49, n = gr - w * 49;
    int b = w >> 6, wi = w & 63;
    int hh = (wi >> 3) * 7 + n / 7 + 3; if (hh >= 56) hh -= 56;
    int ww = (wi & 7) * 7 + (n - (n / 7) * 7) + 3; if (ww >= 56) ww -= 56;
    float* orow = out + ((size_t)b * 3136 + hh * 56 + ww) * 192;
    #pragma unroll
    for (int ct = 0; ct < 12; ct++) {
      int col = ct * 16 + lrow;
      orow[col] = acc[ct][r] + proj_b[col];
    }
  }
}

// ---------------- fused MLP: gelu(h@fc1+b1)@fc2+b2 + xr ----------------
__global__ __launch_bounds__(256) void mlp_kernel(
    const u16* __restrict__ h, const u16* __restrict__ fc1_wT,
    const float* __restrict__ fc1_b, const u16* __restrict__ fc2_wT,
    const float* __restrict__ fc2_b, float* __restrict__ out) {
  __shared__ __align__(16) u16 sA[64 * 200];
  __shared__ __align__(16) u16 sT[64 * 72];
  const int tid = threadIdx.x;
  const int r0 = blockIdx.x * 64;
  {
    const u32* ag = (const u32*)(h + (size_t)r0 * 192);
    u32* d = (u32*)sA;
    for (int i = tid; i < 64 * 96; i += 256) {
      int r = i / 96, c = i - r * 96;
      d[r * 100 + c] = ag[i];
    }
  }
  __syncthreads();
  const int wv = tid >> 6, ln = tid & 63, lrow = ln & 15, quad = ln >> 4;
  f32x4 accOut[12];
  #pragma unroll
  for (int t = 0; t < 12; t++) accOut[t] = (f32x4){0.f, 0.f, 0.f, 0.f};
  for (int ch = 0; ch < 12; ch++) {
    f32x4 accT[4];
    #pragma unroll
    for (int t = 0; t < 4; t++) accT[t] = (f32x4){0.f, 0.f, 0.f, 0.f};
    #pragma unroll
    for (int kc = 0; kc < 6; kc++) {
      bf16x8 af = *(const bf16x8*)(sA + (16 * wv + lrow) * 200 + kc * 32 + quad * 8);
      #pragma unroll
      for (int ct = 0; ct < 4; ct++) {
        bf16x8 bf_ = *(const bf16x8*)(fc1_wT + (size_t)(ch * 64 + ct * 16 + lrow) * 192 + kc * 32 + quad * 8);
        accT[ct] = MFMA16(af, bf_, accT[ct]);
      }
    }
    #pragma unroll
    for (int ct = 0; ct < 4; ct++) {
      int col = ch * 64 + ct * 16 + lrow;
      float bias = fc1_b[col];
      #pragma unroll
      for (int r = 0; r < 4; r++) {
        float v = accT[ct][r] + bias;
        float gl = 0.5f * v * (1.f + erff(v * 0.70710678118654752f));
        sT[(16 * wv + quad * 4 + r) * 72 + ct * 16 + lrow] = f2bf(gl);
      }
    }
    __syncthreads();
    #pragma unroll
    for (int kc = 0; kc < 2; kc++) {
      bf16x8 af = *(const bf16x8*)(sT + (16 * wv + lrow) * 72 + kc * 32 + quad * 8);
      #pragma unroll
      for (int ct = 0; ct < 12; ct++) {
        bf16x8 bf_ = *(const bf16x8*)(fc2_wT + (size_t)(ct * 16 + lrow) * 768 + ch * 64 + kc * 32 + quad * 8);
        accOut[ct] = MFMA16(af, bf_, accOut[ct]);
      }
    }
    __syncthreads();
  }
  #pragma unroll
  for (int r = 0; r < 4; r++) {
    size_t gr = (size_t)r0 + 16 * wv + quad * 4 + r;
    float* orow = out + gr * 192;
    #pragma unroll
    for (int ct = 0; ct < 12; ct++) {
      int col = ct * 16 + lrow;
      orow[col] = orow[col] + accOut[ct][r] + fc2_b[col];
    }
  }
}

extern "C" void kernel_launch(void* const* d_in, const int* in_sizes, int n_in,
                              void* d_out, int out_size, void* d_ws, size_t ws_size,
                              hipStream_t stream) {
  const float* x      = (const float*)d_in[0];
  const float* qkv_w  = (const float*)d_in[1];
  const float* qkv_b  = (const float*)d_in[2];
  const float* proj_w = (const float*)d_in[3];
  const float* proj_b = (const float*)d_in[4];
  const float* n1_g   = (const float*)d_in[5];
  const float* n1_b   = (const float*)d_in[6];
  const float* n2_g   = (const float*)d_in[7];
  const float* n2_b   = (const float*)d_in[8];
  const float* fc1_w  = (const float*)d_in[9];
  const float* fc1_b  = (const float*)d_in[10];
  const float* fc2_w  = (const float*)d_in[11];
  const float* fc2_b  = (const float*)d_in[12];
  const float* amask  = (const float*)d_in[13];
  float* out = (float*)d_out;
  char* ws = (char*)d_ws;

  // workspace layout (bytes)
  u16* xn      = (u16*)(ws + 0);            // 2048*49*192 bf16 = 38,535,168
  u16* attnout = (u16*)(ws + 38535168);     // 38,535,168
  u16* hbuf    = (u16*)(ws + 77070336);     // 38,535,168
  u16* qkv_wT  = (u16*)(ws + 115605504);    // 221,184
  u16* proj_wT = (u16*)(ws + 115826688);    // 73,728
  u16* fc1_wT  = (u16*)(ws + 115900416);    // 294,912
  u16* fc2_wT  = (u16*)(ws + 116195328);    // 294,912  (total ~116.5 MB)

  prep_weights<<<256, 256, 0, stream>>>(qkv_w, proj_w, fc1_w, fc2_w,
                                        qkv_wT, proj_wT, fc1_wT, fc2_wT);
  ln1_kernel<<<100352, 192, 0, stream>>>(x, n1_g, n1_b, xn);
  attn_kernel<<<12288, 256, 0, stream>>>(xn, qkv_wT, qkv_b, amask, attnout);
  proj_kernel<<<1568, 256, 0, stream>>>(attnout, proj_wT, proj_b, out);
  ln2_kernel<<<100352, 192, 0, stream>>>(out, n2_g, n2_b, hbuf);
  mlp_kernel<<<1568, 256, 0, stream>>>(hbuf, fc1_wT, fc1_b, fc2_wT, fc2_b, out);
}

// Round 2
// 909.747 us; speedup vs baseline: 1.2812x; 1.2812x over previous
//
#include <hip/hip_runtime.h>

typedef unsigned short u16;
typedef unsigned int u32;
typedef __bf16 bf16x8 __attribute__((ext_vector_type(8)));
typedef float f32x4 __attribute__((ext_vector_type(4)));

#define MFMA16(a,b,c) __builtin_amdgcn_mfma_f32_16x16x32_bf16((a),(b),(c),0,0,0)

__device__ __forceinline__ u16 f2bf(float x) {
  u32 u = __float_as_uint(x);
  u32 r = (u + 0x7fffu + ((u >> 16) & 1u)) >> 16;
  return (u16)r;
}

// ---------------- weight transpose + bf16 cast ----------------
__global__ __launch_bounds__(256) void prep_weights(
    const float* __restrict__ qkv_w, const float* __restrict__ proj_w,
    const float* __restrict__ fc1_w, const float* __restrict__ fc2_w,
    u16* __restrict__ qkv_wT, u16* __restrict__ proj_wT,
    u16* __restrict__ fc1_wT, u16* __restrict__ fc2_wT) {
  int t0 = blockIdx.x * 256 + threadIdx.x;
  int stride = gridDim.x * 256;
  for (int i = t0; i < 576 * 192; i += stride) {        // qkv_wT [576][192]
    int n = i / 192, k = i - n * 192;
    qkv_wT[i] = f2bf(qkv_w[k * 576 + n]);
  }
  for (int i = t0; i < 192 * 192; i += stride) {        // proj_wT [192][192]
    int n = i / 192, k = i - n * 192;
    proj_wT[i] = f2bf(proj_w[k * 192 + n]);
  }
  for (int i = t0; i < 768 * 192; i += stride) {        // fc1_wT [768][192]
    int n = i / 192, k = i - n * 192;
    fc1_wT[i] = f2bf(fc1_w[k * 768 + n]);
  }
  for (int i = t0; i < 192 * 768; i += stride) {        // fc2_wT [192][768]
    int n = i / 768, k = i - n * 768;
    fc2_wT[i] = f2bf(fc2_w[k * 192 + n]);
  }
}

// ---------------- LN1 + shift + window partition ----------------
__global__ __launch_bounds__(192) void ln1_kernel(
    const float* __restrict__ x, const float* __restrict__ g,
    const float* __restrict__ bb, u16* __restrict__ xn) {
  int row = blockIdx.x;
  int w = row / 49, n = row - w * 49;
  int b = w >> 6, wi = w & 63;
  int hh = (wi >> 3) * 7 + n / 7 + 3; if (hh >= 56) hh -= 56;
  int ww = (wi & 7) * 7 + (n - (n / 7) * 7) + 3; if (ww >= 56) ww -= 56;
  const float* src = x + ((size_t)b * 3136 + hh * 56 + ww) * 192;
  int t = threadIdx.x;
  float v = src[t];
  float a1 = v, a2 = v * v;
  #pragma unroll
  for (int off = 32; off; off >>= 1) {
    a1 += __shfl_down(a1, off);
    a2 += __shfl_down(a2, off);
  }
  __shared__ float rA[3], rB[3];
  if ((t & 63) == 0) { rA[t >> 6] = a1; rB[t >> 6] = a2; }
  __syncthreads();
  float s1 = rA[0] + rA[1] + rA[2];
  float s2 = rB[0] + rB[1] + rB[2];
  float mu = s1 * (1.f / 192.f);
  float var = s2 * (1.f / 192.f) - mu * mu;
  float rs = rsqrtf(var + 1e-5f);
  xn[(size_t)row * 192 + t] = f2bf((v - mu) * rs * g[t] + bb[t]);
}

// ---------------- fused qkv + window attention ----------------
__global__ __launch_bounds__(256) void attn_kernel(
    const u16* __restrict__ xn, const u16* __restrict__ qkv_wT,
    const float* __restrict__ qkv_b, const float* __restrict__ amask,
    u16* __restrict__ attnout) {
  __shared__ __align__(16) char lds[64000];
  u16* sXN = (u16*)lds;                  // [64][200] bf16 (phase A)
  u16* sW  = (u16*)(lds + 25600);        // [96][200] bf16 (phase A)
  u16* sQK = (u16*)lds;                  // [2][64][40] bf16 (phase B+)
  u16* sVT = (u16*)(lds + 10240);        // [32][72] bf16 V^T
  float* sS = (float*)(lds + 15360);     // [64][65] f32
  u16* sP  = (u16*)(lds + 32000);        // [64][72] bf16

  const int tid = threadIdx.x;
  const int blk = blockIdx.x;
  const int w = blk / 6;
  const int hd = blk - w * 6;
  const int wv = tid >> 6;
  const int ln = tid & 63;
  const int lrow = ln & 15;
  const int quad = ln >> 4;

  {
    const u32* xng = (const u32*)(xn + (size_t)w * (49 * 192));
    u32* d = (u32*)sXN;
    for (int i = tid; i < 64 * 96; i += 256) {
      int r = i / 96, c = i - r * 96;
      d[r * 100 + c] = (r < 49) ? xng[r * 96 + c] : 0u;
    }
    const u32* wg = (const u32*)qkv_wT;
    u32* dw = (u32*)sW;
    for (int i = tid; i < 96 * 96; i += 256) {
      int r = i / 96, c = i - r * 96;
      int sr = (r >> 5) * 192 + hd * 32 + (r & 31);
      dw[r * 100 + c] = wg[sr * 96 + c];
    }
  }
  __syncthreads();

  // QKV gemm: 64x96, K=192
  f32x4 accQ[6];
  #pragma unroll
  for (int t = 0; t < 6; t++) accQ[t] = (f32x4){0.f, 0.f, 0.f, 0.f};
  #pragma unroll
  for (int kc = 0; kc < 6; kc++) {
    bf16x8 af = *(const bf16x8*)(sXN + (16 * wv + lrow) * 200 + kc * 32 + quad * 8);
    #pragma unroll
    for (int t = 0; t < 6; t++) {
      bf16x8 bf_ = *(const bf16x8*)(sW + (t * 16 + lrow) * 200 + kc * 32 + quad * 8);
      accQ[t] = MFMA16(af, bf_, accQ[t]);
    }
  }
  __syncthreads();

  #pragma unroll
  for (int t = 0; t < 6; t++) {
    int cc = t * 16 + lrow;
    int sec = cc >> 5;
    int d = cc & 31;
    float bias = qkv_b[sec * 192 + hd * 32 + d];
    #pragma unroll
    for (int r = 0; r < 4; r++) {
      int row = 16 * wv + quad * 4 + r;
      u16 v = f2bf(accQ[t][r] + bias);
      if (sec == 2) sVT[d * 72 + row] = v;
      else sQK[(sec * 64 + row) * 40 + d] = v;
    }
  }
  __syncthreads();

  // S = Q K^T
  f32x4 accS[4];
  #pragma unroll
  for (int t = 0; t < 4; t++) accS[t] = (f32x4){0.f, 0.f, 0.f, 0.f};
  {
    bf16x8 af = *(const bf16x8*)(sQK + (16 * wv + lrow) * 40 + quad * 8);
    #pragma unroll
    for (int mt = 0; mt < 4; mt++) {
      bf16x8 bf_ = *(const bf16x8*)(sQK + (64 + mt * 16 + lrow) * 40 + quad * 8);
      accS[mt] = MFMA16(af, bf_, accS[mt]);
    }
  }
  #pragma unroll
  for (int mt = 0; mt < 4; mt++) {
    #pragma unroll
    for (int r = 0; r < 4; r++)
      sS[(16 * wv + quad * 4 + r) * 65 + mt * 16 + lrow] = accS[mt][r];
  }
  __syncthreads();

  // softmax: 4 threads per row
  {
    int n = tid >> 2;
    int sub = tid & 3;
    u16* prow = sP + n * 72;
    if (n < 49) {
      const float* mrow = amask + ((size_t)(w & 63) * 49 + n) * 49;
      float* srow = sS + n * 65;
      const float scale = 0.17677669529663687f;
      float mx = -1e30f;
      for (int m = sub; m < 49; m += 4) {
        float sv = srow[m] * scale + mrow[m];
        srow[m] = sv;
        mx = fmaxf(mx, sv);
      }
      mx = fmaxf(mx, __shfl_xor(mx, 1));
      mx = fmaxf(mx, __shfl_xor(mx, 2));
      float sum = 0.f;
      for (int m = sub; m < 49; m += 4) {
        float e = __expf(srow[m] - mx);
        srow[m] = e;
        sum += e;
      }
      sum += __shfl_xor(sum, 1);
      sum += __shfl_xor(sum, 2);
      float inv = 1.f / sum;
      for (int m = sub; m < 49; m += 4) prow[m] = f2bf(srow[m] * inv);
      for (int m = 49 + sub; m < 64; m += 4) prow[m] = 0;
    } else {
      for (int m = sub; m < 64; m += 4) prow[m] = 0;
    }
  }
  __syncthreads();

  // O = P V
  f32x4 accO[2];
  accO[0] = (f32x4){0.f, 0.f, 0.f, 0.f};
  accO[1] = (f32x4){0.f, 0.f, 0.f, 0.f};
  #pragma unroll
  for (int kc = 0; kc < 2; kc++) {
    bf16x8 af = *(const bf16x8*)(sP + (16 * wv + lrow) * 72 + kc * 32 + quad * 8);
    #pragma unroll
    for (int ct = 0; ct < 2; ct++) {
      bf16x8 bf_ = *(const bf16x8*)(sVT + (ct * 16 + lrow) * 72 + kc * 32 + quad * 8);
      accO[ct] = MFMA16(af, bf_, accO[ct]);
    }
  }
  #pragma unroll
  for (int ct = 0; ct < 2; ct++) {
    #pragma unroll
    for (int r = 0; r < 4; r++) {
      int row = 16 * wv + quad * 4 + r;
      if (row < 49)
        attnout[((size_t)w * 49 + row) * 192 + hd * 32 + ct * 16 + lrow] =
            f2bf(accO[ct][r]);
    }
  }
}

// ---------------- proj gemm + reverse partition/roll scatter ----------------
// 128 rows/block, 32 rows/wave, single barrier, B from global (L2-hot).
__global__ __launch_bounds__(256) void proj_kernel(
    const u16* __restrict__ attnout, const u16* __restrict__ proj_wT,
    const float* __restrict__ proj_b, float* __restrict__ out) {
  __shared__ __align__(16) u16 sA[128 * 200];
  const int tid = threadIdx.x;
  const int r0 = blockIdx.x * 128;
  {
    const u32* ag = (const u32*)(attnout + (size_t)r0 * 192);
    u32* d = (u32*)sA;
    for (int i = tid; i < 128 * 96; i += 256) {
      int r = i / 96, c = i - r * 96;
      d[r * 100 + c] = ag[i];
    }
  }
  __syncthreads();
  const int wv = tid >> 6, ln = tid & 63, lrow = ln & 15, quad = ln >> 4;
  f32x4 acc[2][12];
  #pragma unroll
  for (int rt = 0; rt < 2; rt++)
    #pragma unroll
    for (int t = 0; t < 12; t++) acc[rt][t] = (f32x4){0.f, 0.f, 0.f, 0.f};
  #pragma unroll
  for (int kc = 0; kc < 6; kc++) {
    bf16x8 a0 = *(const bf16x8*)(sA + (32 * wv + lrow) * 200 + kc * 32 + quad * 8);
    bf16x8 a1 = *(const bf16x8*)(sA + (32 * wv + 16 + lrow) * 200 + kc * 32 + quad * 8);
    #pragma unroll
    for (int ct = 0; ct < 12; ct++) {
      bf16x8 bf_ = *(const bf16x8*)(proj_wT + (size_t)(ct * 16 + lrow) * 192 + kc * 32 + quad * 8);
      acc[0][ct] = MFMA16(a0, bf_, acc[0][ct]);
      acc[1][ct] = MFMA16(a1, bf_, acc[1][ct]);
    }
  }
  #pragma unroll
  for (int rt = 0; rt < 2; rt++) {
    #pragma unroll
    for (int r = 0; r < 4; r++) {
      int gr = r0 + 32 * wv + rt * 16 + quad * 4 + r;
      int w = gr / 49, n = gr - w * 49;
      int b = w >> 6, wi = w & 63;
      int hh = (wi >> 3) * 7 + n / 7 + 3; if (hh >= 56) hh -= 56;
      int ww = (wi & 7) * 7 + (n - (n / 7) * 7) + 3; if (ww >= 56) ww -= 56;
      float* orow = out + ((size_t)b * 3136 + hh * 56 + ww) * 192;
      #pragma unroll
      for (int ct = 0; ct < 12; ct++) {
        int col = ct * 16 + lrow;
        orow[col] = acc[rt][ct][r] + proj_b[col];
      }
    }
  }
}

// ---------------- fused LN2 + MLP ----------------
// 128 rows/block, 32 rows/wave, ONE barrier total; wave-private gelu tile so
// the fc1->fc2 round-trip needs only in-wave lgkmcnt ordering (no syncthreads
// in the 12-chunk loop => weight prefetch stays in flight).
__global__ __launch_bounds__(256, 2) void mlp_kernel(
    const float* __restrict__ xr, const float* __restrict__ g,
    const float* __restrict__ bb,
    const u16* __restrict__ fc1_wT, const float* __restrict__ fc1_b,
    const u16* __restrict__ fc2_wT, const float* __restrict__ fc2_b,
    float* __restrict__ out) {
  __shared__ __align__(16) u16 sA[128 * 200];
  __shared__ __align__(16) u16 sT[4 * 32 * 72];
  const int tid = threadIdx.x;
  const size_t r0 = (size_t)blockIdx.x * 128;

  // fused LN2: 2 threads per row, two passes (2nd pass L1/L2-hot)
  {
    int r = tid >> 1, half = tid & 1;
    const float* src = xr + (r0 + r) * 192 + half * 96;
    float s1 = 0.f, s2 = 0.f;
    #pragma unroll
    for (int i = 0; i < 24; i++) {
      float4 v = ((const float4*)src)[i];
      s1 += v.x + v.y + v.z + v.w;
      s2 += v.x * v.x + v.y * v.y + v.z * v.z + v.w * v.w;
    }
    s1 += __shfl_xor(s1, 1);
    s2 += __shfl_xor(s2, 1);
    float mu = s1 * (1.f / 192.f);
    float var = s2 * (1.f / 192.f) - mu * mu;
    float rs = rsqrtf(var + 1e-5f);
    u16* drow = sA + r * 200 + half * 96;
    #pragma unroll
    for (int i = 0; i < 24; i++) {
      float4 v = ((const float4*)src)[i];
      int c = half * 96 + i * 4;
      ushort4 o;
      o.x = f2bf((v.x - mu) * rs * g[c + 0] + bb[c + 0]);
      o.y = f2bf((v.y - mu) * rs * g[c + 1] + bb[c + 1]);
      o.z = f2bf((v.z - mu) * rs * g[c + 2] + bb[c + 2]);
      o.w = f2bf((v.w - mu) * rs * g[c + 3] + bb[c + 3]);
      *((ushort4*)(drow + i * 4)) = o;
    }
  }
  __syncthreads();

  const int wv = tid >> 6, ln = tid & 63, lrow = ln & 15, quad = ln >> 4;
  u16* sTw = sT + wv * (32 * 72);   // wave-private [32][72]
  f32x4 accOut[2][12];
  #pragma unroll
  for (int rt = 0; rt < 2; rt++)
    #pragma unroll
    for (int t = 0; t < 12; t++) accOut[rt][t] = (f32x4){0.f, 0.f, 0.f, 0.f};

  for (int ch = 0; ch < 12; ch++) {
    f32x4 accT[2][4];
    #pragma unroll
    for (int rt = 0; rt < 2; rt++)
      #pragma unroll
      for (int t = 0; t < 4; t++) accT[rt][t] = (f32x4){0.f, 0.f, 0.f, 0.f};
    #pragma unroll
    for (int kc = 0; kc < 6; kc++) {
      bf16x8 a0 = *(const bf16x8*)(sA + (32 * wv + lrow) * 200 + kc * 32 + quad * 8);
      bf16x8 a1 = *(const bf16x8*)(sA + (32 * wv + 16 + lrow) * 200 + kc * 32 + quad * 8);
      #pragma unroll
      for (int ct = 0; ct < 4; ct++) {
        bf16x8 b = *(const bf16x8*)(fc1_wT + (size_t)(ch * 64 + ct * 16 + lrow) * 192 + kc * 32 + quad * 8);
        accT[0][ct] = MFMA16(a0, b, accT[0][ct]);
        accT[1][ct] = MFMA16(a1, b, accT[1][ct]);
      }
    }
    #pragma unroll
    for (int rt = 0; rt < 2; rt++) {
      #pragma unroll
      for (int ct = 0; ct < 4; ct++) {
        int col = ct * 16 + lrow;
        float bias = fc1_b[ch * 64 + col];
        #pragma unroll
        for (int r = 0; r < 4; r++) {
          float v = accT[rt][ct][r] + bias;
          float gl = 0.5f * v * (1.f + erff(v * 0.70710678118654752f));
          sTw[(rt * 16 + quad * 4 + r) * 72 + col] = f2bf(gl);
        }
      }
    }
    #pragma unroll
    for (int kc = 0; kc < 2; kc++) {
      bf16x8 a0 = *(const bf16x8*)(sTw + lrow * 72 + kc * 32 + quad * 8);
      bf16x8 a1 = *(const bf16x8*)(sTw + (16 + lrow) * 72 + kc * 32 + quad * 8);
      #pragma unroll
      for (int ct = 0; ct < 12; ct++) {
        bf16x8 b = *(const bf16x8*)(fc2_wT + (size_t)(ct * 16 + lrow) * 768 + ch * 64 + kc * 32 + quad * 8);
        accOut[0][ct] = MFMA16(a0, b, accOut[0][ct]);
        accOut[1][ct] = MFMA16(a1, b, accOut[1][ct]);
      }
    }
  }

  #pragma unroll
  for (int rt = 0; rt < 2; rt++) {
    #pragma unroll
    for (int r = 0; r < 4; r++) {
      float* orow = out + (r0 + 32 * wv + rt * 16 + quad * 4 + r) * 192;
      #pragma unroll
      for (int ct = 0; ct < 12; ct++) {
        int col = ct * 16 + lrow;
        orow[col] = orow[col] + accOut[rt][ct][r] + fc2_b[col];
      }
    }
  }
}

extern "C" void kernel_launch(void* const* d_in, const int* in_sizes, int n_in,
                              void* d_out, int out_size, void* d_ws, size_t ws_size,
                              hipStream_t stream) {
  const float* x      = (const float*)d_in[0];
  const float* qkv_w  = (const float*)d_in[1];
  const float* qkv_b  = (const float*)d_in[2];
  const float* proj_w = (const float*)d_in[3];
  const float* proj_b = (const float*)d_in[4];
  const float* n1_g   = (const float*)d_in[5];
  const float* n1_b   = (const float*)d_in[6];
  const float* n2_g   = (const float*)d_in[7];
  const float* n2_b   = (const float*)d_in[8];
  const float* fc1_w  = (const float*)d_in[9];
  const float* fc1_b  = (const float*)d_in[10];
  const float* fc2_w  = (const float*)d_in[11];
  const float* fc2_b  = (const float*)d_in[12];
  const float* amask  = (const float*)d_in[13];
  float* out = (float*)d_out;
  char* ws = (char*)d_ws;

  // workspace layout (bytes)
  u16* xn      = (u16*)(ws + 0);            // 38,535,168
  u16* attnout = (u16*)(ws + 38535168);     // 38,535,168
  u16* qkv_wT  = (u16*)(ws + 77070336);     // 221,184
  u16* proj_wT = (u16*)(ws + 77291520);     // 73,728
  u16* fc1_wT  = (u16*)(ws + 77365248);     // 294,912
  u16* fc2_wT  = (u16*)(ws + 77660160);     // 294,912  (total ~78 MB)

  prep_weights<<<256, 256, 0, stream>>>(qkv_w, proj_w, fc1_w, fc2_w,
                                        qkv_wT, proj_wT, fc1_wT, fc2_wT);
  ln1_kernel<<<100352, 192, 0, stream>>>(x, n1_g, n1_b, xn);
  attn_kernel<<<12288, 256, 0, stream>>>(xn, qkv_wT, qkv_b, amask, attnout);
  proj_kernel<<<784, 256, 0, stream>>>(attnout, proj_wT, proj_b, out);
  mlp_kernel<<<784, 256, 0, stream>>>(out, n2_g, n2_b,
                                      fc1_wT, fc1_b, fc2_wT, fc2_b, out);
}

// Round 4
// 719.043 us; speedup vs baseline: 1.6210x; 1.2652x over previous
//
#include <hip/hip_runtime.h>

typedef unsigned short u16;
typedef unsigned int u32;
typedef __bf16 bf16x8 __attribute__((ext_vector_type(8)));
typedef float f32x4 __attribute__((ext_vector_type(4)));

#define MFMA16(a,b,c) __builtin_amdgcn_mfma_f32_16x16x32_bf16((a),(b),(c),0,0,0)

__device__ __forceinline__ u16 f2bf(float x) {
  u32 u = __float_as_uint(x);
  u32 r = (u + 0x7fffu + ((u >> 16) & 1u)) >> 16;
  return (u16)r;
}

// ---------------- weight transpose + bf16 cast ----------------
__global__ __launch_bounds__(256) void prep_weights(
    const float* __restrict__ qkv_w, const float* __restrict__ proj_w,
    const float* __restrict__ fc1_w, const float* __restrict__ fc2_w,
    u16* __restrict__ qkv_wT, u16* __restrict__ proj_wT,
    u16* __restrict__ fc1_wT, u16* __restrict__ fc2_wT) {
  int t0 = blockIdx.x * 256 + threadIdx.x;
  int stride = gridDim.x * 256;
  for (int i = t0; i < 576 * 192; i += stride) {
    int n = i / 192, k = i - n * 192;
    qkv_wT[i] = f2bf(qkv_w[k * 576 + n]);
  }
  for (int i = t0; i < 192 * 192; i += stride) {
    int n = i / 192, k = i - n * 192;
    proj_wT[i] = f2bf(proj_w[k * 192 + n]);
  }
  for (int i = t0; i < 768 * 192; i += stride) {
    int n = i / 192, k = i - n * 192;
    fc1_wT[i] = f2bf(fc1_w[k * 768 + n]);
  }
  for (int i = t0; i < 192 * 768; i += stride) {
    int n = i / 768, k = i - n * 768;
    fc2_wT[i] = f2bf(fc2_w[k * 192 + n]);
  }
}

// ---------------- fused LN1(+shift/window gather) + QKV GEMM ----------------
// Row-continuous: 128 rows/block, 32 rows/wave, ONE barrier. Output layout per
// (window,head) block of 4928 u16: Q[49][32] @0, K[49][32] @1568, V^T[32][56] @3136.
__global__ __launch_bounds__(256) void qkv_ln_kernel(
    const float* __restrict__ x, const float* __restrict__ g,
    const float* __restrict__ bb,
    const u16* __restrict__ qkv_wT, const float* __restrict__ qkv_b,
    u16* __restrict__ qkvb, int rowbase, int wbase) {
  __shared__ __align__(16) u16 sA[128 * 200];
  const int tid = threadIdx.x;
  const int r0 = rowbase + blockIdx.x * 128;

  // fused LN1 with shifted-window gather: 2 threads per row
  {
    int r = tid >> 1, half = tid & 1;
    int gr = r0 + r;
    int w = gr / 49, n = gr - w * 49;
    int b = w >> 6, wi = w & 63;
    int rr = n / 7, cc = n - rr * 7;
    int hh = (wi >> 3) * 7 + rr + 3; if (hh >= 56) hh -= 56;
    int ww = (wi & 7) * 7 + cc + 3; if (ww >= 56) ww -= 56;
    const float* src = x + ((size_t)b * 3136 + hh * 56 + ww) * 192 + half * 96;
    float s1 = 0.f, s2 = 0.f;
    #pragma unroll
    for (int i = 0; i < 24; i++) {
      float4 v = ((const float4*)src)[i];
      s1 += v.x + v.y + v.z + v.w;
      s2 += v.x * v.x + v.y * v.y + v.z * v.z + v.w * v.w;
    }
    s1 += __shfl_xor(s1, 1);
    s2 += __shfl_xor(s2, 1);
    float mu = s1 * (1.f / 192.f);
    float var = s2 * (1.f / 192.f) - mu * mu;
    float rs = rsqrtf(var + 1e-5f);
    u16* drow = sA + r * 200 + half * 96;
    #pragma unroll
    for (int i = 0; i < 24; i++) {
      float4 v = ((const float4*)src)[i];
      int c = half * 96 + i * 4;
      ushort4 o;
      o.x = f2bf((v.x - mu) * rs * g[c + 0] + bb[c + 0]);
      o.y = f2bf((v.y - mu) * rs * g[c + 1] + bb[c + 1]);
      o.z = f2bf((v.z - mu) * rs * g[c + 2] + bb[c + 2]);
      o.w = f2bf((v.w - mu) * rs * g[c + 3] + bb[c + 3]);
      *((ushort4*)(drow + i * 4)) = o;
    }
  }
  __syncthreads();

  const int wv = tid >> 6, ln = tid & 63, lrow = ln & 15, quad = ln >> 4;

  // precompute per (rt,reg) output row -> (window,token) offsets
  u32 qkoff[8], voff[8];
  #pragma unroll
  for (int rt = 0; rt < 2; rt++) {
    #pragma unroll
    for (int reg = 0; reg < 4; reg++) {
      int grow = r0 + 32 * wv + 16 * rt + quad * 4 + reg;
      int w_ = grow / 49, n_ = grow - w_ * 49;
      u32 wb = (u32)(w_ - wbase) * 29568u;  // *6*4928
      qkoff[rt * 4 + reg] = wb + (u32)n_ * 32u;
      voff[rt * 4 + reg] = wb + (u32)n_;
    }
  }

  for (int ct = 0; ct < 36; ct++) {
    f32x4 acc0 = (f32x4){0.f, 0.f, 0.f, 0.f};
    f32x4 acc1 = (f32x4){0.f, 0.f, 0.f, 0.f};
    #pragma unroll
    for (int kc = 0; kc < 6; kc++) {
      bf16x8 a0 = *(const bf16x8*)(sA + (32 * wv + lrow) * 200 + kc * 32 + quad * 8);
      bf16x8 a1 = *(const bf16x8*)(sA + (32 * wv + 16 + lrow) * 200 + kc * 32 + quad * 8);
      bf16x8 bw = *(const bf16x8*)(qkv_wT + (size_t)(16 * ct + lrow) * 192 + kc * 32 + quad * 8);
      acc0 = MFMA16(a0, bw, acc0);
      acc1 = MFMA16(a1, bw, acc1);
    }
    int sec = ct / 12, ccc = ct - sec * 12;
    int head = ccc >> 1, d0 = (ccc & 1) * 16;
    int col = d0 + lrow;
    float bias = qkv_b[sec * 192 + head * 32 + col];
    u32 hoff = (u32)head * 4928u;
    if (sec < 2) {
      u32 coff = hoff + (u32)sec * 1568u + (u32)col;
      #pragma unroll
      for (int reg = 0; reg < 4; reg++) {
        qkvb[qkoff[reg] + coff] = f2bf(acc0[reg] + bias);
        qkvb[qkoff[4 + reg] + coff] = f2bf(acc1[reg] + bias);
      }
    } else {
      u32 coff = hoff + 3136u + (u32)col * 56u;
      #pragma unroll
      for (int reg = 0; reg < 4; reg++) {
        qkvb[voff[reg] + coff] = f2bf(acc0[reg] + bias);
        qkvb[voff[4 + reg] + coff] = f2bf(acc1[reg] + bias);
      }
    }
  }
}

// ---------------- window attention: 1 block/window, 1 wave/head ----------------
// S^T = K.Q^T in C-layout, in-register softmax (in-lane + shfl over quad bits),
// arithmetic Swin mask, wave-private P tile in LDS, O = P.V. NO barriers.
__global__ __launch_bounds__(384) void attn2_kernel(
    const u16* __restrict__ qkvb, u16* __restrict__ attnout, int wbase) {
  __shared__ __align__(16) u16 sP[6 * 64 * 72];
  const int tid = threadIdx.x;
  const int wv = tid >> 6;          // head
  const int ln = tid & 63;
  const int lrow = ln & 15;
  const int quad = ln >> 4;
  const int wl = blockIdx.x;
  const int w = wbase + wl;
  const int wi = w & 63;
  const int wr = wi >> 3, wc = wi & 7;
  const u16* base = qkvb + (size_t)(wl * 6 + wv) * 4928;
  u16* sPw = sP + wv * (64 * 72);
  const f32x4 zero4 = {0.f, 0.f, 0.f, 0.f};

  // S^T tiles: S[rt][ct][reg] = S^T[m=16rt+quad*4+reg][n=16ct+lrow]
  bf16x8 kf[4];
  #pragma unroll
  for (int rt = 0; rt < 4; rt++)
    kf[rt] = *(const bf16x8*)(base + 1568 + (16 * rt + lrow) * 32 + quad * 8);
  f32x4 S[4][4];
  #pragma unroll
  for (int ct = 0; ct < 4; ct++) {
    bf16x8 qf = *(const bf16x8*)(base + (16 * ct + lrow) * 32 + quad * 8);
    #pragma unroll
    for (int rt = 0; rt < 4; rt++)
      S[rt][ct] = MFMA16(kf[rt], qf, zero4);
  }

  // region codes for n (query) per ct
  int hbn[4], wbn[4];
  #pragma unroll
  for (int ct = 0; ct < 4; ct++) {
    int n = 16 * ct + lrow;
    int rn = (n * 9363) >> 16;
    int cn = n - 7 * rn;
    hbn[ct] = (wr < 7) ? 0 : ((rn >= 4) ? 2 : 1);
    wbn[ct] = (wc < 7) ? 0 : ((cn >= 4) ? 2 : 1);
  }

  const float scale = 0.17677669529663687f;
  float mx[4] = {-1e30f, -1e30f, -1e30f, -1e30f};
  #pragma unroll
  for (int rt = 0; rt < 4; rt++) {
    #pragma unroll
    for (int reg = 0; reg < 4; reg++) {
      int m = 16 * rt + quad * 4 + reg;
      int rm = (m * 9363) >> 16;
      int cm = m - 7 * rm;
      int hbm = (wr < 7) ? 0 : ((rm >= 4) ? 2 : 1);
      int wbm = (wc < 7) ? 0 : ((cm >= 4) ? 2 : 1);
      bool padm = (m >= 49);
      #pragma unroll
      for (int ct = 0; ct < 4; ct++) {
        float sv = S[rt][ct][reg] * scale +
                   (((hbm != hbn[ct]) || (wbm != wbn[ct])) ? -100.f : 0.f);
        sv = padm ? -1e30f : sv;
        S[rt][ct][reg] = sv;
        mx[ct] = fmaxf(mx[ct], sv);
      }
    }
  }
  #pragma unroll
  for (int ct = 0; ct < 4; ct++) {
    mx[ct] = fmaxf(mx[ct], __shfl_xor(mx[ct], 16));
    mx[ct] = fmaxf(mx[ct], __shfl_xor(mx[ct], 32));
  }
  float sum[4] = {0.f, 0.f, 0.f, 0.f};
  #pragma unroll
  for (int rt = 0; rt < 4; rt++)
    #pragma unroll
    for (int reg = 0; reg < 4; reg++)
      #pragma unroll
      for (int ct = 0; ct < 4; ct++) {
        float e = __expf(S[rt][ct][reg] - mx[ct]);
        S[rt][ct][reg] = e;
        sum[ct] += e;
      }
  float inv[4];
  #pragma unroll
  for (int ct = 0; ct < 4; ct++) {
    sum[ct] += __shfl_xor(sum[ct], 16);
    sum[ct] += __shfl_xor(sum[ct], 32);
    inv[ct] = 1.f / sum[ct];
  }

  // write P row-major [n][m], stride 72; lane's 4 regs are 4 consecutive m
  #pragma unroll
  for (int rt = 0; rt < 4; rt++) {
    #pragma unroll
    for (int ct = 0; ct < 4; ct++) {
      ushort4 o;
      o.x = f2bf(S[rt][ct][0] * inv[ct]);
      o.y = f2bf(S[rt][ct][1] * inv[ct]);
      o.z = f2bf(S[rt][ct][2] * inv[ct]);
      o.w = f2bf(S[rt][ct][3] * inv[ct]);
      *((ushort4*)(sPw + (16 * ct + lrow) * 72 + 16 * rt + quad * 4)) = o;
    }
  }

  // O = P . V : A-frags from sPw, B-frags V^T from global
  f32x4 accO[4][2];
  #pragma unroll
  for (int rt = 0; rt < 4; rt++)
    #pragma unroll
    for (int cd = 0; cd < 2; cd++) accO[rt][cd] = zero4;
  #pragma unroll
  for (int kc = 0; kc < 2; kc++) {
    bf16x8 vf[2];
    #pragma unroll
    for (int cd = 0; cd < 2; cd++)
      vf[cd] = *(const bf16x8*)(base + 3136 + (16 * cd + lrow) * 56 + kc * 32 + quad * 8);
    #pragma unroll
    for (int rt = 0; rt < 4; rt++) {
      bf16x8 af = *(const bf16x8*)(sPw + (16 * rt + lrow) * 72 + kc * 32 + quad * 8);
      #pragma unroll
      for (int cd = 0; cd < 2; cd++)
        accO[rt][cd] = MFMA16(af, vf[cd], accO[rt][cd]);
    }
  }

  #pragma unroll
  for (int rt = 0; rt < 4; rt++) {
    #pragma unroll
    for (int reg = 0; reg < 4; reg++) {
      int n = 16 * rt + quad * 4 + reg;
      if (n < 49) {
        #pragma unroll
        for (int cd = 0; cd < 2; cd++)
          attnout[(size_t)(w * 49 + n) * 192 + wv * 32 + 16 * cd + lrow] =
              f2bf(accO[rt][cd][reg]);
      }
    }
  }
}

// ---------------- proj gemm + reverse partition/roll scatter ----------------
__global__ __launch_bounds__(256) void proj_kernel(
    const u16* __restrict__ attnout, const u16* __restrict__ proj_wT,
    const float* __restrict__ proj_b, float* __restrict__ out) {
  __shared__ __align__(16) u16 sA[128 * 200];
  const int tid = threadIdx.x;
  const int r0 = blockIdx.x * 128;
  {
    const u32* ag = (const u32*)(attnout + (size_t)r0 * 192);
    u32* d = (u32*)sA;
    for (int i = tid; i < 128 * 96; i += 256) {
      int r = i / 96, c = i - r * 96;
      d[r * 100 + c] = ag[i];
    }
  }
  __syncthreads();
  const int wv = tid >> 6, ln = tid & 63, lrow = ln & 15, quad = ln >> 4;
  f32x4 acc[2][12];
  #pragma unroll
  for (int rt = 0; rt < 2; rt++)
    #pragma unroll
    for (int t = 0; t < 12; t++) acc[rt][t] = (f32x4){0.f, 0.f, 0.f, 0.f};
  #pragma unroll
  for (int kc = 0; kc < 6; kc++) {
    bf16x8 a0 = *(const bf16x8*)(sA + (32 * wv + lrow) * 200 + kc * 32 + quad * 8);
    bf16x8 a1 = *(const bf16x8*)(sA + (32 * wv + 16 + lrow) * 200 + kc * 32 + quad * 8);
    #pragma unroll
    for (int ct = 0; ct < 12; ct++) {
      bf16x8 bf_ = *(const bf16x8*)(proj_wT + (size_t)(ct * 16 + lrow) * 192 + kc * 32 + quad * 8);
      acc[0][ct] = MFMA16(a0, bf_, acc[0][ct]);
      acc[1][ct] = MFMA16(a1, bf_, acc[1][ct]);
    }
  }
  #pragma unroll
  for (int rt = 0; rt < 2; rt++) {
    #pragma unroll
    for (int r = 0; r < 4; r++) {
      int gr = r0 + 32 * wv + rt * 16 + quad * 4 + r;
      int w = gr / 49, n = gr - w * 49;
      int b = w >> 6, wi = w & 63;
      int hh = (wi >> 3) * 7 + n / 7 + 3; if (hh >= 56) hh -= 56;
      int ww = (wi & 7) * 7 + (n - (n / 7) * 7) + 3; if (ww >= 56) ww -= 56;
      float* orow = out + ((size_t)b * 3136 + hh * 56 + ww) * 192;
      #pragma unroll
      for (int ct = 0; ct < 12; ct++) {
        int col = ct * 16 + lrow;
        orow[col] = acc[rt][ct][r] + proj_b[col];
      }
    }
  }
}

// ---------------- fused LN2 + MLP ----------------
__global__ __launch_bounds__(256, 2) void mlp_kernel(
    const float* __restrict__ xr, const float* __restrict__ g,
    const float* __restrict__ bb,
    const u16* __restrict__ fc1_wT, const float* __restrict__ fc1_b,
    const u16* __restrict__ fc2_wT, const float* __restrict__ fc2_b,
    float* __restrict__ out) {
  __shared__ __align__(16) u16 sA[128 * 200];
  __shared__ __align__(16) u16 sT[4 * 32 * 72];
  const int tid = threadIdx.x;
  const size_t r0 = (size_t)blockIdx.x * 128;

  {
    int r = tid >> 1, half = tid & 1;
    const float* src = xr + (r0 + r) * 192 + half * 96;
    float s1 = 0.f, s2 = 0.f;
    #pragma unroll
    for (int i = 0; i < 24; i++) {
      float4 v = ((const float4*)src)[i];
      s1 += v.x + v.y + v.z + v.w;
      s2 += v.x * v.x + v.y * v.y + v.z * v.z + v.w * v.w;
    }
    s1 += __shfl_xor(s1, 1);
    s2 += __shfl_xor(s2, 1);
    float mu = s1 * (1.f / 192.f);
    float var = s2 * (1.f / 192.f) - mu * mu;
    float rs = rsqrtf(var + 1e-5f);
    u16* drow = sA + r * 200 + half * 96;
    #pragma unroll
    for (int i = 0; i < 24; i++) {
      float4 v = ((const float4*)src)[i];
      int c = half * 96 + i * 4;
      ushort4 o;
      o.x = f2bf((v.x - mu) * rs * g[c + 0] + bb[c + 0]);
      o.y = f2bf((v.y - mu) * rs * g[c + 1] + bb[c + 1]);
      o.z = f2bf((v.z - mu) * rs * g[c + 2] + bb[c + 2]);
      o.w = f2bf((v.w - mu) * rs * g[c + 3] + bb[c + 3]);
      *((ushort4*)(drow + i * 4)) = o;
    }
  }
  __syncthreads();

  const int wv = tid >> 6, ln = tid & 63, lrow = ln & 15, quad = ln >> 4;
  u16* sTw = sT + wv * (32 * 72);
  f32x4 accOut[2][12];
  #pragma unroll
  for (int rt = 0; rt < 2; rt++)
    #pragma unroll
    for (int t = 0; t < 12; t++) accOut[rt][t] = (f32x4){0.f, 0.f, 0.f, 0.f};

  for (int ch = 0; ch < 12; ch++) {
    f32x4 accT[2][4];
    #pragma unroll
    for (int rt = 0; rt < 2; rt++)
      #pragma unroll
      for (int t = 0; t < 4; t++) accT[rt][t] = (f32x4){0.f, 0.f, 0.f, 0.f};
    #pragma unroll
    for (int kc = 0; kc < 6; kc++) {
      bf16x8 a0 = *(const bf16x8*)(sA + (32 * wv + lrow) * 200 + kc * 32 + quad * 8);
      bf16x8 a1 = *(const bf16x8*)(sA + (32 * wv + 16 + lrow) * 200 + kc * 32 + quad * 8);
      #pragma unroll
      for (int ct = 0; ct < 4; ct++) {
        bf16x8 b = *(const bf16x8*)(fc1_wT + (size_t)(ch * 64 + ct * 16 + lrow) * 192 + kc * 32 + quad * 8);
        accT[0][ct] = MFMA16(a0, b, accT[0][ct]);
        accT[1][ct] = MFMA16(a1, b, accT[1][ct]);
      }
    }
    #pragma unroll
    for (int rt = 0; rt < 2; rt++) {
      #pragma unroll
      for (int ct = 0; ct < 4; ct++) {
        int col = ct * 16 + lrow;
        float bias = fc1_b[ch * 64 + col];
        #pragma unroll
        for (int r = 0; r < 4; r++) {
          float v = accT[rt][ct][r] + bias;
          float gl = 0.5f * v * (1.f + erff(v * 0.70710678118654752f));
          sTw[(rt * 16 + quad * 4 + r) * 72 + col] = f2bf(gl);
        }
      }
    }
    #pragma unroll
    for (int kc = 0; kc < 2; kc++) {
      bf16x8 a0 = *(const bf16x8*)(sTw + lrow * 72 + kc * 32 + quad * 8);
      bf16x8 a1 = *(const bf16x8*)(sTw + (16 + lrow) * 72 + kc * 32 + quad * 8);
      #pragma unroll
      for (int ct = 0; ct < 12; ct++) {
        bf16x8 b = *(const bf16x8*)(fc2_wT + (size_t)(ct * 16 + lrow) * 768 + ch * 64 + kc * 32 + quad * 8);
        accOut[0][ct] = MFMA16(a0, b, accOut[0][ct]);
        accOut[1][ct] = MFMA16(a1, b, accOut[1][ct]);
      }
    }
  }

  #pragma unroll
  for (int rt = 0; rt < 2; rt++) {
    #pragma unroll
    for (int r = 0; r < 4; r++) {
      float* orow = out + (r0 + 32 * wv + rt * 16 + quad * 4 + r) * 192;
      #pragma unroll
      for (int ct = 0; ct < 12; ct++) {
        int col = ct * 16 + lrow;
        orow[col] = orow[col] + accOut[rt][ct][r] + fc2_b[col];
      }
    }
  }
}

extern "C" void kernel_launch(void* const* d_in, const int* in_sizes, int n_in,
                              void* d_out, int out_size, void* d_ws, size_t ws_size,
                              hipStream_t stream) {
  const float* x      = (const float*)d_in[0];
  const float* qkv_w  = (const float*)d_in[1];
  const float* qkv_b  = (const float*)d_in[2];
  const float* proj_w = (const float*)d_in[3];
  const float* proj_b = (const float*)d_in[4];
  const float* n1_g   = (const float*)d_in[5];
  const float* n1_b   = (const float*)d_in[6];
  const float* n2_g   = (const float*)d_in[7];
  const float* n2_b   = (const float*)d_in[8];
  const float* fc1_w  = (const float*)d_in[9];
  const float* fc1_b  = (const float*)d_in[10];
  const float* fc2_w  = (const float*)d_in[11];
  const float* fc2_b  = (const float*)d_in[12];
  float* out = (float*)d_out;
  char* ws = (char*)d_ws;

  // workspace layout (bytes)
  u16* qkvb    = (u16*)(ws + 0);            // 1024*6*4928*2 = 60,555,264
  u16* attnout = (u16*)(ws + 60555264);     // 38,535,168 -> ends 99,090,432
  u16* qkv_wT  = (u16*)(ws + 99090432);     // 221,184
  u16* proj_wT = (u16*)(ws + 99311616);     // 73,728
  u16* fc1_wT  = (u16*)(ws + 99385344);     // 294,912
  u16* fc2_wT  = (u16*)(ws + 99680256);     // 294,912 -> ends 99,975,168 (~100 MB)

  prep_weights<<<256, 256, 0, stream>>>(qkv_w, proj_w, fc1_w, fc2_w,
                                        qkv_wT, proj_wT, fc1_wT, fc2_wT);
  for (int hf = 0; hf < 2; hf++) {
    qkv_ln_kernel<<<392, 256, 0, stream>>>(x, n1_g, n1_b, qkv_wT, qkv_b,
                                           qkvb, hf * 50176, hf * 1024);
    attn2_kernel<<<1024, 384, 0, stream>>>(qkvb, attnout, hf * 1024);
  }
  proj_kernel<<<784, 256, 0, stream>>>(attnout, proj_wT, proj_b, out);
  mlp_kernel<<<784, 256, 0, stream>>>(out, n2_g, n2_b,
                                      fc1_wT, fc1_b, fc2_wT, fc2_b, out);
}